// Round 2
// baseline (9194.839 us; speedup 1.0000x reference)
//
#include <hip/hip_runtime.h>
#include <stdint.h>

#define HDIM 256
#define SEQ  784
#define NB   256
#define NCLS 10
#define NTHR 512
#define KMLO 96              // MFMA K-slice = [96,160): straddles hs pad cleanly
#define AQ   30              // arch-VGPR weight quads per thread (120 VGPRs)
#define LQ2  18              // LDS weight quads per thread (147,456 B)
#define VQ   48              // VALU quads per thread (AQ+LQ2); K in [0,96) U [160,256)
#define NTILE 8              // MFMA 16-row tiles per wave (8 waves x 8 = 64 tiles = 1024 rows)

typedef _Float16 half2_t __attribute__((ext_vector_type(2)));
typedef _Float16 half8_t __attribute__((ext_vector_type(8)));
typedef float    f32x4_t __attribute__((ext_vector_type(4)));

__device__ __forceinline__ half2_t u2h(uint32_t u) {
    union { uint32_t u; half2_t h; } v; v.u = u; return v.h;
}
__device__ __forceinline__ uint32_t pkf16(float a, float b) {
    union { half2_t h; uint32_t u; } v;
    v.h.x = (_Float16)a; v.h.y = (_Float16)b; return v.u;
}
__device__ __forceinline__ half8_t u4h8(uint4 u) {
    union { uint4 u; half8_t h; } v; v.u = u; return v.h;
}

#if __has_builtin(__builtin_amdgcn_fdot2)
__device__ __forceinline__ float dot2(uint32_t h, uint32_t w, float acc) {
    return __builtin_amdgcn_fdot2(u2h(h), u2h(w), acc, false);
}
#else
__device__ __forceinline__ float dot2(uint32_t h, uint32_t w, float acc) {
    half2_t hv = u2h(h), wv = u2h(w);
    acc = fmaf((float)hv.x, (float)wv.x, acc);
    return fmaf((float)hv.y, (float)wv.y, acc);
}
#endif

#if __has_builtin(__builtin_amdgcn_rcpf)
__device__ __forceinline__ float fast_rcp(float x) { return __builtin_amdgcn_rcpf(x); }
#else
__device__ __forceinline__ float fast_rcp(float x) { return 1.f / x; }
#endif

__device__ __forceinline__ float sigmoid_f(float x) {
    return fast_rcp(1.f + __expf(-x));
}
__device__ __forceinline__ float tanh_f(float x) {
    return fmaf(2.f, fast_rcp(1.f + __expf(-2.f * x)), -1.f);
}

// VALU weights: WP[q*NTHR + t], t=(r<<1)|kh: quad {G,I,F,O} f16-pairs, row r,
// k = (kh ? 160 : 0) + 2q, q in [0,48)
__global__ __launch_bounds__(NTHR) void pack_w16(
    const float* __restrict__ Wg, const float* __restrict__ Wi,
    const float* __restrict__ Wf, const float* __restrict__ Wo,
    uint4* __restrict__ WP)
{
    const int q = blockIdx.x;          // 0..47
    const int t = threadIdx.x;         // 0..511
    const int r = t >> 1, kh = t & 1;
    const int k = (kh ? 160 : 0) + 2 * q;
    const int s = r * HDIM + k;
    uint4 v;
    v.x = pkf16(Wg[s], Wg[s + 1]);
    v.y = pkf16(Wi[s], Wi[s + 1]);
    v.z = pkf16(Wf[s], Wf[s + 1]);
    v.w = pkf16(Wo[s], Wo[s + 1]);
    WP[q * NTHR + t] = v;
}

// MFMA A-fragments for K in [96,160). v_mfma_f32_16x16x32_f16 A layout:
// lane l: row = l&15, k = KMLO + (l>>4)*8 + 2j + h  (reg j in [0,4), half h).
// Gate-row space rho = gate*256 + r; tile tau covers rows [tau*16, tau*16+16).
// WPA[(tau*2 + s)*64 + lane], s = k-step (0: k 96..127, 1: k 128..159).
__global__ __launch_bounds__(NTHR) void pack_wmfma(
    const float* __restrict__ Wg, const float* __restrict__ Wi,
    const float* __restrict__ Wf, const float* __restrict__ Wo,
    uint4* __restrict__ WPA)
{
    const int t = threadIdx.x;
    const int lane = t & 63;
    const int s    = (t >> 6) & 1;
    const int tau  = blockIdx.x * 4 + (t >> 7);   // 0..63
    const int rho  = tau * 16 + (lane & 15);
    const int gate = rho >> 8;
    const int r    = rho & 255;
    const int k0   = KMLO + s * 32 + ((lane >> 4) & 3) * 8;
    const float* W = (gate == 0) ? Wg : (gate == 1) ? Wi : (gate == 2) ? Wf : Wo;
    const float* src = W + r * HDIM + k0;
    uint4 v;
    v.x = pkf16(src[0], src[1]);
    v.y = pkf16(src[2], src[3]);
    v.z = pkf16(src[4], src[5]);
    v.w = pkf16(src[6], src[7]);
    WPA[(tau * 2 + s) * 64 + lane] = v;
}

__global__ void __launch_bounds__(NTHR)
__attribute__((amdgpu_waves_per_eu(2, 2)))   // 2 waves/EU -> 256 unified VGPR budget
lstm_f16(
    const float* __restrict__ x,
    const float* __restrict__ Wgx, const float* __restrict__ bg_,
    const float* __restrict__ Wix, const float* __restrict__ bi_,
    const float* __restrict__ Wfx, const float* __restrict__ bf_,
    const float* __restrict__ Wox, const float* __restrict__ bo_,
    const float* __restrict__ Wph, const float* __restrict__ bp_,
    const uint4* __restrict__ WP,
    float* __restrict__ out)
{
    __shared__ uint4 lws[LQ2 * NTHR];                      // 147,456 B
    __shared__ float xs[SEQ];                              //   3,136 B
    __shared__ __align__(16) uint32_t hs[2][136];          //   1,088 B (f16 h, dbuf, +pad @128)
    __shared__ float hfin[HDIM];                           //   1,024 B
    __shared__ __align__(16) float mpart[4][HDIM];         //   4,096 B (MFMA partials [gate][r])

    const int t  = threadIdx.x;
    const int b  = blockIdx.x;
    const int r  = t >> 1;
    const int kh = t & 1;
    const int ln = t & 63;          // lane in wave
    const int wv = t >> 6;          // wave id 0..7

    for (int i = t; i < SEQ; i += NTHR) xs[i] = x[b * SEQ + i];
    if (t < 136) hs[0][t] = 0u;

    #pragma unroll
    for (int c = 0; c < LQ2; ++c) lws[c * NTHR + t] = WP[c * NTHR + t];

    uint4 wq[AQ];
    #pragma unroll
    for (int i = 0; i < AQ; ++i) wq[i] = WP[(LQ2 + i) * NTHR + t];

    // MFMA A-fragments (consumed only by MFMA -> regalloc should place in AGPRs)
    const uint4* WPA = WP + VQ * NTHR;
    half8_t afr[NTILE][2];
    #pragma unroll
    for (int i = 0; i < NTILE; ++i) {
        afr[i][0] = u4h8(WPA[((wv * NTILE + i) * 2 + 0) * 64 + ln]);
        afr[i][1] = u4h8(WPA[((wv * NTILE + i) * 2 + 1) * 64 + ln]);
    }

    // x-term + bias on kh==0 lane only (shfl_xor reduce sums both partials)
    const float xsc = (kh == 0) ? 1.f : 0.f;
    const float wgxe = xsc * Wgx[r], wixe = xsc * Wix[r];
    const float wfxe = xsc * Wfx[r], woxe = xsc * Wox[r];
    const float bge = xsc * bg_[b], bie = xsc * bi_[b];
    const float bfe = xsc * bf_[b], boe = xsc * bo_[b];

    const f32x4_t zz = {0.f, 0.f, 0.f, 0.f};

    float cst = 0.f, hcur = 0.f;

    __syncthreads();

    #pragma unroll 1
    for (int ts = 0; ts < SEQ; ++ts) {
        const int cur = ts & 1;
        const char* hb = (const char*)&hs[cur][0];

        const float xt = xs[ts];
        float sg = fmaf(wgxe, xt, bge);
        float si = fmaf(wixe, xt, bie);
        float sf = fmaf(wfxe, xt, bfe);
        float so = fmaf(woxe, xt, boe);

        // --- MFMA slice: B-fragments = h[96..159] broadcast across cols ---
        // lane l reads h[96 + (l>>4)*8 .. +7] (byte 192+..) and h[128 + (l>>4)*8 ..] (byte 272+..)
        const int l4 = (ln >> 4) * 16;
        const half8_t b0 = *(const half8_t*)(hb + 192 + l4);
        const half8_t b1 = *(const half8_t*)(hb + 272 + l4);

        f32x4_t acc[NTILE];
        #pragma unroll
        for (int i = 0; i < NTILE; ++i) {
            acc[i] = __builtin_amdgcn_mfma_f32_16x16x32_f16(afr[i][0], b0, zz, 0, 0, 0);
            acc[i] = __builtin_amdgcn_mfma_f32_16x16x32_f16(afr[i][1], b1, acc[i], 0, 0, 0);
        }

        // --- VALU slice: K in [0,96) (kh=0) or [160,256) (kh=1) ---
        const char* hv = hb + (kh ? 336 : 0);
        #pragma unroll
        for (int ch = 0; ch < VQ / 4; ++ch) {
            const uint4 hh = *(const uint4*)(hv + 16 * ch);
            const uint32_t hx[4] = { hh.x, hh.y, hh.z, hh.w };
            #pragma unroll
            for (int e = 0; e < 4; ++e) {
                const int q = ch * 4 + e;
                uint4 w;
                if (q < LQ2) w = lws[q * NTHR + t];
                else         w = wq[q - LQ2];
                sg = dot2(hx[e], w.x, sg);
                si = dot2(hx[e], w.y, si);
                sf = dot2(hx[e], w.z, sf);
                so = dot2(hx[e], w.w, so);
            }
        }

        // --- MFMA partial store: col-0 lanes hold rows tau*16+(ln>>4)*4+reg ---
        if ((ln & 15) == 0) {
            #pragma unroll
            for (int i = 0; i < NTILE; ++i) {
                const int tau  = wv * NTILE + i;
                const int gate = tau >> 4;
                const int rr   = (tau & 15) * 16 + (ln >> 4) * 4;
                *(f32x4_t*)&mpart[gate][rr] = acc[i];
            }
        }
        __syncthreads();   // bar1: mpart visible to all

        sg += __shfl_xor(sg, 1);
        si += __shfl_xor(si, 1);
        sf += __shfl_xor(sf, 1);
        so += __shfl_xor(so, 1);

        sg += mpart[0][r];
        si += mpart[1][r];
        sf += mpart[2][r];
        so += mpart[3][r];

        const float g  = tanh_f(sg);
        const float iv = sigmoid_f(si);
        const float fv = sigmoid_f(sf);
        const float ov = sigmoid_f(so);
        cst  = fmaf(g, iv, cst * fv);
        hcur = tanh_f(cst) * ov;

        // padded write: h[r] at half-index r (+8 past the 4-dword pad for r>=128)
        if (kh == 0) ((_Float16*)&hs[cur ^ 1][0])[r + ((r >> 7) << 3)] = (_Float16)hcur;

        __syncthreads();   // bar2: hs[cur^1] ready; mpart reads done before next writes
    }

    if (kh == 0) hfin[r] = hcur;
    __syncthreads();

    if (t < NCLS) {
        float acc = bp_[b];
        #pragma unroll 4
        for (int k = 0; k < HDIM; ++k) acc = fmaf(Wph[t * HDIM + k], hfin[k], acc);
        out[b * NCLS + t] = acc;
    }
}

// Fallback (no workspace): fp32 weights streamed from L2. Correctness insurance only.
__global__ __launch_bounds__(HDIM) void lstm_fb(
    const float* __restrict__ x,
    const float* __restrict__ Wgx, const float* __restrict__ Wgh, const float* __restrict__ bg_,
    const float* __restrict__ Wix, const float* __restrict__ Wih, const float* __restrict__ bi_,
    const float* __restrict__ Wfx, const float* __restrict__ Wfh, const float* __restrict__ bf_,
    const float* __restrict__ Wox, const float* __restrict__ Woh, const float* __restrict__ bo_,
    const float* __restrict__ Wph, const float* __restrict__ bp_,
    float* __restrict__ out)
{
    __shared__ float xs[SEQ];
    __shared__ float hsv[HDIM];
    const int r = threadIdx.x, b = blockIdx.x;
    for (int i = r; i < SEQ; i += HDIM) xs[i] = x[b * SEQ + i];
    hsv[r] = 0.f;
    float c = 0.f;
    const float wgx = Wgx[r], wix = Wix[r], wfx = Wfx[r], wox = Wox[r];
    const float bg = bg_[b], bi = bi_[b], bfv = bf_[b], bo = bo_[b];
    __syncthreads();
    for (int ts = 0; ts < SEQ; ++ts) {
        const float xt = xs[ts];
        float ag = fmaf(wgx, xt, bg);
        float ai = fmaf(wix, xt, bi);
        float af = fmaf(wfx, xt, bfv);
        float ao = fmaf(wox, xt, bo);
        #pragma unroll 4
        for (int k = 0; k < HDIM; ++k) {
            const float hv = hsv[k];
            ag = fmaf(Wgh[r * HDIM + k], hv, ag);
            ai = fmaf(Wih[r * HDIM + k], hv, ai);
            af = fmaf(Wfh[r * HDIM + k], hv, af);
            ao = fmaf(Woh[r * HDIM + k], hv, ao);
        }
        const float g  = tanhf(ag);
        const float iv = 1.f / (1.f + expf(-ai));
        const float fv = 1.f / (1.f + expf(-af));
        const float ov = 1.f / (1.f + expf(-ao));
        c = fmaf(g, iv, c * fv);
        const float hn = tanhf(c) * ov;
        __syncthreads();
        hsv[r] = hn;
        __syncthreads();
    }
    if (r < NCLS) {
        float acc = bp_[b];
        for (int k = 0; k < HDIM; ++k) acc = fmaf(Wph[r * HDIM + k], hsv[k], acc);
        out[b * NCLS + r] = acc;
    }
}

extern "C" void kernel_launch(void* const* d_in, const int* in_sizes, int n_in,
                              void* d_out, int out_size, void* d_ws, size_t ws_size,
                              hipStream_t stream) {
    const float* x   = (const float*)d_in[0];
    const float* Wgx = (const float*)d_in[1];
    const float* Wgh = (const float*)d_in[2];
    const float* bg  = (const float*)d_in[3];
    const float* Wix = (const float*)d_in[4];
    const float* Wih = (const float*)d_in[5];
    const float* bi  = (const float*)d_in[6];
    const float* Wfx = (const float*)d_in[7];
    const float* Wfh = (const float*)d_in[8];
    const float* bf  = (const float*)d_in[9];
    const float* Wox = (const float*)d_in[10];
    const float* Woh = (const float*)d_in[11];
    const float* bo  = (const float*)d_in[12];
    const float* Wph = (const float*)d_in[13];
    const float* bp  = (const float*)d_in[14];
    float* out = (float*)d_out;

    // WP: 48*512 VALU quads, then 64*2*64 MFMA fragment quads = 32768 uint4 = 512 KB
    const size_t need = (size_t)(VQ * NTHR + 64 * 2 * 64) * sizeof(uint4);
    if (ws_size >= need) {
        uint4* WP = (uint4*)d_ws;
        pack_w16<<<dim3(VQ), dim3(NTHR), 0, stream>>>(Wgh, Wih, Wfh, Woh, WP);
        pack_wmfma<<<dim3(16), dim3(NTHR), 0, stream>>>(Wgh, Wih, Wfh, Woh, WP + VQ * NTHR);
        lstm_f16<<<dim3(NB), dim3(NTHR), 0, stream>>>(
            x, Wgx, bg, Wix, bi, Wfx, bf, Wox, bo, Wph, bp, (const uint4*)WP, out);
    } else {
        lstm_fb<<<dim3(NB), dim3(HDIM), 0, stream>>>(
            x, Wgx, Wgh, bg, Wix, Wih, bi, Wfx, Wfh, bf, Wox, Woh, bo, Wph, bp, out);
    }
}